// Round 2
// baseline (1520.042 us; speedup 1.0000x reference)
//
#include <hip/hip_runtime.h>
#include <math.h>

#define NIMG 128
#define HW   256
#define NPX  (HW*HW)

__device__ __forceinline__ int refl_idx(int t) {
  return t < 0 ? -t : (t > 255 ? 510 - t : t);
}

// ---------------- Kernel A: per-image mean / inv_std (ddof=1) ----------------
__global__ __launch_bounds__(256)
void stats_kernel(const float* __restrict__ pred, const float* __restrict__ targ,
                  float* __restrict__ stats)
{
  const int b = blockIdx.x;        // 0..255
  const int which = b >> 7;        // 0 pred, 1 targ
  const int img = b & 127;
  const float4* src = (const float4*)((which ? targ : pred) + (size_t)img * NPX);
  const int t = threadIdx.x;
  double s = 0.0, s2 = 0.0;
  for (int i = t; i < NPX/4; i += 256) {
    float4 v = src[i];
    s  += (double)v.x + (double)v.y + (double)v.z + (double)v.w;
    s2 += (double)v.x*v.x + (double)v.y*v.y + (double)v.z*v.z + (double)v.w*v.w;
  }
  __shared__ double rs[256], rs2[256];
  rs[t] = s; rs2[t] = s2;
  __syncthreads();
  for (int off = 128; off > 0; off >>= 1) {
    if (t < off) { rs[t] += rs[t+off]; rs2[t] += rs2[t+off]; }
    __syncthreads();
  }
  if (t == 0) {
    const double n = (double)NPX;
    double mean = rs[0] / n;
    double var = (rs2[0] - n*mean*mean) / (n - 1.0);
    stats[(which*NIMG + img)*2 + 0] = (float)mean;
    stats[(which*NIMG + img)*2 + 1] = (float)(1.0 / sqrt(var));
  }
}

// ---------------- Kernel B: SSIM for one ks (all 5 sigmas) ----------------
// grid: 128 imgs * 4 superstrips = 512 blocks, 256 threads.
// Each block: one image, 64 output rows (4 strips of 16), loops 5 sigmas.
template<int KS>
__global__ __launch_bounds__(256, 2)
void ssim_kernel(const float* __restrict__ pred, const float* __restrict__ targ,
                 const float* __restrict__ stats, float* __restrict__ partial)
{
  constexpr int PAD = (KS - 1) / 2;
  constexpr float C1f = (float)(0.01 * 0.01);
  constexpr float C2f = (float)(0.03 * 0.03);

  const int bid = blockIdx.x;
  const int img = bid >> 2;
  const int ss  = bid & 3;
  const int t = threadIdx.x;

  __shared__ float xs[28][256];     // staged standardized pred rows (reflect)
  __shared__ float ys[28][256];     // staged standardized target rows
  __shared__ float vf[5][4][272];   // vertical-blur fields, cols -8..263 (+8 offset)
  __shared__ float gw[5][16];       // gaussian weights per sigma
  __shared__ float red[256];

  // gaussian weights in double to match numpy
  if (t < 5) {
    const double sigs[5] = {0.8, 1.2, 1.5, 1.8, 2.0};
    double sig = sigs[t];
    double tmp[KS]; double sum = 0.0;
    #pragma unroll
    for (int a = 0; a < KS; ++a) {
      double d = (double)(a - PAD) / sig;
      double e = exp(-0.5 * d * d);
      tmp[a] = e; sum += e;
    }
    #pragma unroll
    for (int a = 0; a < KS; ++a) gw[t][a] = (float)(tmp[a] / sum);
  }

  const float mx = stats[(0*NIMG + img)*2 + 0];
  const float ix = stats[(0*NIMG + img)*2 + 1];
  const float my = stats[(1*NIMG + img)*2 + 0];
  const float iy = stats[(1*NIMG + img)*2 + 1];

  const float4* p4 = (const float4*)(pred + (size_t)img * NPX);
  const float4* t4 = (const float4*)(targ + (size_t)img * NPX);

  float acc = 0.f;

  for (int st = 0; st < 4; ++st) {
    const int r0 = ss*64 + st*16;          // output rows r0 .. r0+15
    __syncthreads();                       // xs/ys reuse + gw visibility
    // stage rows r0-6 .. r0+21 (28 rows, reflect), standardized
    for (int i = t; i < 28*64; i += 256) {
      const int row = i >> 6, c4 = i & 63;
      const int gr = refl_idx(r0 - 6 + row);
      float4 a = p4[gr*64 + c4];
      float4 b = t4[gr*64 + c4];
      a.x = (a.x - mx)*ix; a.y = (a.y - mx)*ix; a.z = (a.z - mx)*ix; a.w = (a.w - mx)*ix;
      b.x = (b.x - my)*iy; b.y = (b.y - my)*iy; b.z = (b.z - my)*iy; b.w = (b.w - my)*iy;
      *(float4*)&xs[row][c4*4] = a;
      *(float4*)&ys[row][c4*4] = b;
    }
    __syncthreads();

    for (int si = 0; si < 5; ++si) {
      float g[KS];
      #pragma unroll
      for (int a = 0; a < KS; ++a) g[a] = gw[si][a];

      for (int ch = 0; ch < 4; ++ch) {
        // ---- vertical pass: thread = logical col, 4 output rows ----
        for (int cc = t - 8; cc < 264; cc += 256) {
          const int rc = cc < 0 ? -cc : (cc > 255 ? 510 - cc : cc);
          float amx[4] = {0,0,0,0}, amy[4] = {0,0,0,0};
          float axx[4] = {0,0,0,0}, ayy[4] = {0,0,0,0}, axy[4] = {0,0,0,0};
          const int base = ch*4 + 6 - PAD;   // xs row index of (rr=0, tap a=0)
          #pragma unroll
          for (int i2 = 0; i2 < KS + 3; ++i2) {
            const float xv = xs[base + i2][rc];
            const float yv = ys[base + i2][rc];
            const float xx = xv*xv, yy = yv*yv, xy = xv*yv;
            #pragma unroll
            for (int rr = 0; rr < 4; ++rr) {
              const int a = i2 - rr;
              if (a >= 0 && a < KS) {
                amx[rr] += g[a]*xv; amy[rr] += g[a]*yv;
                axx[rr] += g[a]*xx; ayy[rr] += g[a]*yy; axy[rr] += g[a]*xy;
              }
            }
          }
          #pragma unroll
          for (int rr = 0; rr < 4; ++rr) {
            vf[0][rr][cc+8] = amx[rr]; vf[1][rr][cc+8] = amy[rr];
            vf[2][rr][cc+8] = axx[rr]; vf[3][rr][cc+8] = ayy[rr];
            vf[4][rr][cc+8] = axy[rr];
          }
        }
        __syncthreads();

        // ---- horizontal pass + smap: thread = (row rr, 4 consecutive cols) ----
        {
          const int rr = t >> 6;
          const int c0 = (t & 63) * 4;
          const int r  = r0 + ch*4 + rr;
          float h[5][4];
          #pragma unroll
          for (int f = 0; f < 5; ++f) {
            float wv[20];
            #pragma unroll
            for (int j = 0; j < 5; ++j) {
              if (j >= (8 - PAD)/4 && j <= (11 + PAD)/4) {
                const float4 v = *(const float4*)&vf[f][rr][c0 + 4*j];
                wv[4*j+0] = v.x; wv[4*j+1] = v.y; wv[4*j+2] = v.z; wv[4*j+3] = v.w;
              }
            }
            #pragma unroll
            for (int p = 0; p < 4; ++p) {
              float s = 0.f;
              #pragma unroll
              for (int b = 0; b < KS; ++b)
                s += g[b] * wv[8 - PAD + p + b];
              h[f][p] = s;
            }
          }
          const bool rok = (r >= PAD) && (r < HW - PAD);
          #pragma unroll
          for (int p = 0; p < 4; ++p) {
            const int c = c0 + p;
            if (rok && c >= PAD && c < HW - PAD) {
              const float hx = h[0][p], hy = h[1][p];
              const float hxx = h[2][p], hyy = h[3][p], hxy = h[4][p];
              const float sx = hxx - hx*hx, sy = hyy - hy*hy, sxy = hxy - hx*hy;
              const float num = (2.f*hx*hy + C1f) * (2.f*sxy + C2f);
              const float den = (hx*hx + hy*hy + C1f) * (sx + sy + C2f);
              acc += num / den;
            }
          }
        }
        __syncthreads();
      } // ch
    } // si
  } // st

  red[t] = acc;
  __syncthreads();
  for (int off = 128; off > 0; off >>= 1) {
    if (t < off) red[t] += red[t+off];
    __syncthreads();
  }
  if (t == 0) {
    constexpr float npix = (float)((HW - 2*PAD) * (HW - 2*PAD));
    partial[bid] = red[0] / (npix * 25.f * 128.f);
  }
}

// ---------------- Kernel C: final deterministic reduction ----------------
__global__ __launch_bounds__(256)
void reduce_kernel(const float* __restrict__ partial, float* __restrict__ out)
{
  const int t = threadIdx.x;
  double s = 0.0;
  for (int i = t; i < 5*512; i += 256) s += (double)partial[i];
  __shared__ double red[256];
  red[t] = s;
  __syncthreads();
  for (int off = 128; off > 0; off >>= 1) {
    if (t < off) red[t] += red[t+off];
    __syncthreads();
  }
  if (t == 0) out[0] = (float)(0.5 - 0.5 * red[0]);
}

extern "C" void kernel_launch(void* const* d_in, const int* in_sizes, int n_in,
                              void* d_out, int out_size, void* d_ws, size_t ws_size,
                              hipStream_t stream) {
  const float* pred = (const float*)d_in[0];
  const float* targ = (const float*)d_in[1];
  float* out = (float*)d_out;
  float* ws = (float*)d_ws;
  float* stats   = ws;          // 512 floats
  float* partial = ws + 512;    // 5*512 floats

  stats_kernel<<<256, 256, 0, stream>>>(pred, targ, stats);
  ssim_kernel<5> <<<512, 256, 0, stream>>>(pred, targ, stats, partial + 0*512);
  ssim_kernel<7> <<<512, 256, 0, stream>>>(pred, targ, stats, partial + 1*512);
  ssim_kernel<9> <<<512, 256, 0, stream>>>(pred, targ, stats, partial + 2*512);
  ssim_kernel<11><<<512, 256, 0, stream>>>(pred, targ, stats, partial + 3*512);
  ssim_kernel<13><<<512, 256, 0, stream>>>(pred, targ, stats, partial + 4*512);
  reduce_kernel<<<1, 256, 0, stream>>>(partial, out);
}